// Round 1
// baseline (40.101 us; speedup 1.0000x reference)
//
#include <hip/hip_runtime.h>
#include <cstdint>

#define K_DIM 1024
#define N_DIM 128
#define BM 64
#define BK 64

typedef __attribute__((ext_vector_type(8))) short bf16x8;
typedef __attribute__((ext_vector_type(4))) float f32x4;
typedef __attribute__((ext_vector_type(4))) int i32x4;
typedef unsigned short u16;
typedef unsigned int u32;

__device__ __forceinline__ float pwbq(float w) {
  w = fminf(fmaxf(w, -1.0f), 1.0f);
  return rintf(w * 127.0f) * (1.0f / 127.0f);
}

// float -> bf16 round-to-nearest-even (finite inputs only)
__device__ __forceinline__ u16 f2bf(float f) {
  union { float f; u32 u; } v; v.f = f;
  u32 r = v.u + 0x7FFFu + ((v.u >> 16) & 1u);
  return (u16)(r >> 16);
}

// Quantize W [K][N] f32 -> Wt [N][K] bf16 (transposed for contiguous-k fragment reads)
__global__ __launch_bounds__(256) void quantW_kernel(const float* __restrict__ W,
                                                     u16* __restrict__ Wt) {
  int e = blockIdx.x * 256 + threadIdx.x;  // 0 .. K*N-1
  int k = e >> 7;                          // N = 128
  int n = e & 127;
  Wt[n * K_DIM + k] = f2bf(pwbq(W[e]));
}

// GEMM: out[M][128] = x[M][1024] @ Wq + bq
// 256 threads (4 waves, 2x2 over 64x128 tile), double-buffered LDS, BK=64.
template <bool PREQ>
__global__ __launch_bounds__(256, 2) void pwb_gemm(
    const float* __restrict__ x,
    const u16* __restrict__ Wt,    // PREQ: bf16 [N][K]
    const float* __restrict__ W,   // !PREQ: f32 [K][N]
    const float* __restrict__ bias,
    float* __restrict__ out) {

  // A: f32 [64 rows][64 k], linear chunks, source-swizzled for conflict-free reads.
  // B: bf16 [128 cols][72 k] (pad 64->72 breaks 128B-stride conflicts).
  __shared__ __align__(16) float As[2][BM * BK];
  __shared__ __align__(16) u16   Bs[2][N_DIM * 72];

  const int tid  = threadIdx.x;
  const int lane = tid & 63;
  const int wid  = tid >> 6;
  const int wm   = wid >> 1;   // 0..1 : 32-row half
  const int wn   = wid & 1;    // 0..1 : 64-col half
  const int m0   = blockIdx.x * BM;
  const int l15  = lane & 15;
  const int lg   = lane >> 4;  // 0..3

  auto stageA = [&](int s, int kt) {
    const float* xb = x + (size_t)m0 * K_DIM + kt * BK;
#pragma unroll
    for (int i = 0; i < 4; ++i) {
      int cd = i * 256 + tid;                 // dest 16B-chunk index (linear LDS)
      int cs = cd ^ ((cd >> 4) & 7);          // inverse-swizzled source chunk
      const float* src = xb + (cs >> 4) * K_DIM + (cs & 15) * 4;
      __builtin_amdgcn_global_load_lds(
          (const __attribute__((address_space(1))) void*)src,
          (__attribute__((address_space(3))) void*)(&As[s][cd * 4]),
          16, 0, 0);
    }
  };

  auto stageB = [&](int s, int kt) {
    const int n  = tid & 127;
    const int kh = tid >> 7;  // 0..1 (32 k each)
    u16* dst = &Bs[s][n * 72 + kh * 32];
    if constexpr (PREQ) {
      const u16* src = Wt + (size_t)n * K_DIM + kt * BK + kh * 32;
      i32x4 v0 = *(const i32x4*)(src + 0);
      i32x4 v1 = *(const i32x4*)(src + 8);
      i32x4 v2 = *(const i32x4*)(src + 16);
      i32x4 v3 = *(const i32x4*)(src + 24);
      *(i32x4*)(dst + 0)  = v0;
      *(i32x4*)(dst + 8)  = v1;
      *(i32x4*)(dst + 16) = v2;
      *(i32x4*)(dst + 24) = v3;
    } else {
      const float* src = W + (size_t)(kt * BK + kh * 32) * N_DIM + n;
      union { i32x4 v[4]; u16 h[32]; } pk;
#pragma unroll
      for (int i = 0; i < 32; ++i) pk.h[i] = f2bf(pwbq(src[i * N_DIM]));
#pragma unroll
      for (int c = 0; c < 4; ++c) *(i32x4*)(dst + c * 8) = pk.v[c];
    }
  };

  f32x4 acc[2][4] = {};

  stageA(0, 0);
  stageB(0, 0);
  __syncthreads();

  const int NIT = K_DIM / BK;  // 16
#pragma unroll 2
  for (int kt = 0; kt < NIT; ++kt) {
    const int cur = kt & 1;
    if (kt + 1 < NIT) {   // issue next-tile staging; overlaps with compute below
      stageA(cur ^ 1, kt + 1);
      stageB(cur ^ 1, kt + 1);
    }

#pragma unroll
    for (int kk = 0; kk < 2; ++kk) {
      bf16x8 a[2];
#pragma unroll
      for (int q = 0; q < 2; ++q) {
        int row  = wm * 32 + q * 16 + l15;
        int base = row * 256 + kk * 128 + lg * 32;   // byte offset (linear)
        int sw   = (row & 7) << 4;                   // XOR swizzle
        f32x4 f0 = *(const f32x4*)((const char*)&As[cur][0] + (base ^ sw));
        f32x4 f1 = *(const f32x4*)((const char*)&As[cur][0] + ((base + 16) ^ sw));
        union { bf16x8 v; u16 h[8]; } pa;
#pragma unroll
        for (int j = 0; j < 4; ++j) {
          pa.h[j]     = f2bf(f0[j]);
          pa.h[4 + j] = f2bf(f1[j]);
        }
        a[q] = pa.v;
      }
      bf16x8 bfr[4];
#pragma unroll
      for (int f = 0; f < 4; ++f) {
        int col = wn * 64 + f * 16 + l15;
        bfr[f] = *(const bf16x8*)(&Bs[cur][col * 72 + kk * 32 + lg * 8]);
      }
#pragma unroll
      for (int q = 0; q < 2; ++q)
#pragma unroll
        for (int f = 0; f < 4; ++f)
          acc[q][f] = __builtin_amdgcn_mfma_f32_16x16x32_bf16(a[q], bfr[f], acc[q][f], 0, 0, 0);
    }
    __syncthreads();
  }

  // epilogue: C/D layout col=lane&15, row=(lane>>4)*4+j (guide m89/m91)
  float bq[4];
#pragma unroll
  for (int f = 0; f < 4; ++f) bq[f] = pwbq(bias[wn * 64 + f * 16 + l15]);

#pragma unroll
  for (int q = 0; q < 2; ++q) {
    int gr0 = m0 + wm * 32 + q * 16 + lg * 4;
#pragma unroll
    for (int f = 0; f < 4; ++f) {
      int gc = wn * 64 + f * 16 + l15;
#pragma unroll
      for (int j = 0; j < 4; ++j) {
        out[(size_t)(gr0 + j) * N_DIM + gc] = acc[q][f][j] + bq[f];
      }
    }
  }
}

extern "C" void kernel_launch(void* const* d_in, const int* in_sizes, int n_in,
                              void* d_out, int out_size, void* d_ws, size_t ws_size,
                              hipStream_t stream) {
  const float* x = (const float*)d_in[0];
  const float* W = (const float*)d_in[1];
  const float* b = (const float*)d_in[2];
  float* out = (float*)d_out;

  const int M = in_sizes[0] / K_DIM;   // 32768
  const int grid = M / BM;             // 512

  const size_t need = (size_t)K_DIM * N_DIM * sizeof(u16);  // 256 KiB
  if (d_ws != nullptr && ws_size >= need) {
    u16* Wt = (u16*)d_ws;
    quantW_kernel<<<(K_DIM * N_DIM) / 256, 256, 0, stream>>>(W, Wt);
    pwb_gemm<true><<<grid, 256, 0, stream>>>(x, Wt, nullptr, b, out);
  } else {
    pwb_gemm<false><<<grid, 256, 0, stream>>>(x, nullptr, W, b, out);
  }
}

// Round 2
// 35.695 us; speedup vs baseline: 1.1234x; 1.1234x over previous
//
#include <hip/hip_runtime.h>
#include <cstdint>

#define K_DIM 1024
#define N_DIM 128
#define BM 64
#define BK 32
#define NT (K_DIM / BK)   // 32 K-tiles

typedef __attribute__((ext_vector_type(8))) short bf16x8;
typedef __attribute__((ext_vector_type(4))) float f32x4;
typedef unsigned short u16;
typedef unsigned int u32;

__device__ __forceinline__ float pwbq(float w) {
  w = fminf(fmaxf(w, -1.0f), 1.0f);
  return rintf(w * 127.0f) * (1.0f / 127.0f);
}

// float -> bf16 round-to-nearest-even (finite inputs only)
__device__ __forceinline__ u16 f2bf(float f) {
  union { float f; u32 u; } v; v.f = f;
  u32 r = v.u + 0x7FFFu + ((v.u >> 16) & 1u);
  return (u16)(r >> 16);
}

// Build Wimg: quantized W as bf16, arranged per K-tile in the exact LDS image
// order with the read-side XOR swizzle baked in (both-sides-or-neither rule).
// Half index H: t=H>>12, h=H&4095, col=h>>5, jimg=h&31,
//   j = jimg ^ ((col&3)<<3), k = t*BK+j, value = q(W[k][col]).
__global__ __launch_bounds__(256) void quantW_kernel(const float* __restrict__ W,
                                                     u16* __restrict__ Wimg) {
  int H = blockIdx.x * 256 + threadIdx.x;   // 0 .. 131071
  int t = H >> 12;
  int h = H & 4095;
  int col = h >> 5;
  int j = (h & 31) ^ ((col & 3) << 3);
  int k = t * BK + j;
  Wimg[H] = f2bf(pwbq(W[k * N_DIM + col]));
}

// Correctness-insurance fallback (only if d_ws is unusably small).
__global__ __launch_bounds__(256) void naive_kernel(const float* __restrict__ x,
                                                    const float* __restrict__ W,
                                                    const float* __restrict__ b,
                                                    float* __restrict__ out, int total) {
  int idx = blockIdx.x * 256 + threadIdx.x;
  if (idx >= total) return;
  int m = idx >> 7, n = idx & 127;
  float acc = pwbq(b[n]);
  for (int k = 0; k < K_DIM; ++k)
    acc = fmaf(x[(size_t)m * K_DIM + k], pwbq(W[k * N_DIM + n]), acc);
  out[idx] = acc;
}

// out[M][128] = x[M][1024] @ Wq + bq
// 256 threads (4 waves, 2x2 over 64x128), 4-deep LDS ring, depth-2 prefetch,
// counted vmcnt (never 0 in steady state), one raw s_barrier per K-tile.
__global__ __launch_bounds__(256, 2) void pwb_gemm(
    const float* __restrict__ x,
    const u16* __restrict__ Wimg,   // bf16, LDS-image order, swizzle baked in
    const float* __restrict__ bias,
    float* __restrict__ out) {

  // A: f32 [64 rows][32 k] per stage (8 KB); B: bf16 [128 cols][32 k] (8 KB).
  __shared__ __align__(16) float As[4][BM * BK];
  __shared__ __align__(16) u16   Bs[4][N_DIM * BK];

  const int tid  = threadIdx.x;
  const int lane = tid & 63;
  const int wid  = tid >> 6;
  const int wm   = wid >> 1;   // 0..1 : 32-row half
  const int wn   = wid & 1;    // 0..1 : 64-col half
  const int m0   = blockIdx.x * BM;
  const int l15  = lane & 15;
  const int lg   = lane >> 4;  // 0..3

  auto stage = [&](int s, int t) {
    // A tile: 512 16B chunks; image chunk cd holds logical chunk cd^(row&7)
    // within its row (inverse of the (row&7)<<4 read swizzle).
#pragma unroll
    for (int i = 0; i < 2; ++i) {
      int cd  = i * 256 + tid;
      int row = cd >> 3;
      int cs  = (cd & 7) ^ (row & 7);
      const float* srcA = x + (size_t)(m0 + row) * K_DIM + t * BK + cs * 4;
      __builtin_amdgcn_global_load_lds(
          (const __attribute__((address_space(1))) void*)srcA,
          (__attribute__((address_space(3))) void*)(&As[s][cd * 4]), 16, 0, 0);
    }
    // B tile: Wimg already in LDS order -> pure linear coalesced copy.
#pragma unroll
    for (int i = 0; i < 2; ++i) {
      int cd = i * 256 + tid;
      const u16* srcB = Wimg + (size_t)t * (N_DIM * BK) + cd * 8;
      __builtin_amdgcn_global_load_lds(
          (const __attribute__((address_space(1))) void*)srcB,
          (__attribute__((address_space(3))) void*)(&Bs[s][cd * 8]), 16, 0, 0);
    }
  };

  f32x4 acc[2][4] = {};

  stage(0, 0);
  stage(1, 1);

#pragma unroll 2
  for (int t = 0; t < NT; ++t) {
    const int buf = t & 3;
    if (t + 2 < NT) {
      stage((t + 2) & 3, t + 2);
      // A(t),B(t) are the oldest; leave the 8 just-issued (t+2) in flight.
      asm volatile("s_waitcnt vmcnt(8)" ::: "memory");
    } else if (t + 1 < NT) {
      asm volatile("s_waitcnt vmcnt(4)" ::: "memory");   // leave tile t+1 in flight
    } else {
      asm volatile("s_waitcnt vmcnt(0)" ::: "memory");   // last tile: drain
    }
    asm volatile("s_barrier" ::: "memory");

    // A fragments: k = lg*8 + j, swizzled read (row&7)<<4
    bf16x8 a[2];
#pragma unroll
    for (int q = 0; q < 2; ++q) {
      int row  = wm * 32 + q * 16 + l15;
      int base = row * 128 + lg * 32;
      int sw   = (row & 7) << 4;
      f32x4 f0 = *(const f32x4*)((const char*)&As[buf][0] + (base ^ sw));
      f32x4 f1 = *(const f32x4*)((const char*)&As[buf][0] + ((base + 16) ^ sw));
      union { bf16x8 v; u16 h[8]; } pa;
#pragma unroll
      for (int j = 0; j < 4; ++j) {
        pa.h[j]     = f2bf(f0[j]);
        pa.h[4 + j] = f2bf(f1[j]);
      }
      a[q] = pa.v;
    }

    // B fragments: swizzle baked into the image: half = col*32 + (lg*8 ^ ((col&3)<<3))
    bf16x8 bfr[4];
#pragma unroll
    for (int f = 0; f < 4; ++f) {
      int col  = wn * 64 + f * 16 + l15;
      int hoff = col * 32 + ((lg * 8) ^ ((col & 3) << 3));
      bfr[f] = *(const bf16x8*)(&Bs[buf][hoff]);
    }

#pragma unroll
    for (int q = 0; q < 2; ++q)
#pragma unroll
      for (int f = 0; f < 4; ++f)
        acc[q][f] = __builtin_amdgcn_mfma_f32_16x16x32_bf16(a[q], bfr[f], acc[q][f], 0, 0, 0);
  }

  // epilogue: C/D layout col=lane&15, row=(lane>>4)*4+j
  float bq[4];
#pragma unroll
  for (int f = 0; f < 4; ++f) bq[f] = pwbq(bias[wn * 64 + f * 16 + l15]);

#pragma unroll
  for (int q = 0; q < 2; ++q) {
    int gr0 = m0 + wm * 32 + q * 16 + lg * 4;
#pragma unroll
    for (int f = 0; f < 4; ++f) {
      int gc = wn * 64 + f * 16 + l15;
#pragma unroll
      for (int j = 0; j < 4; ++j) {
        out[(size_t)(gr0 + j) * N_DIM + gc] = acc[q][f][j] + bq[f];
      }
    }
  }
}

extern "C" void kernel_launch(void* const* d_in, const int* in_sizes, int n_in,
                              void* d_out, int out_size, void* d_ws, size_t ws_size,
                              hipStream_t stream) {
  const float* x = (const float*)d_in[0];
  const float* W = (const float*)d_in[1];
  const float* b = (const float*)d_in[2];
  float* out = (float*)d_out;

  const int M = in_sizes[0] / K_DIM;   // 32768
  const int grid = M / BM;             // 512

  const size_t need = (size_t)K_DIM * N_DIM * sizeof(u16);  // 256 KiB
  if (d_ws != nullptr && ws_size >= need) {
    u16* Wimg = (u16*)d_ws;
    quantW_kernel<<<(K_DIM * N_DIM) / 256, 256, 0, stream>>>(W, Wimg);
    pwb_gemm<<<grid, 256, 0, stream>>>(x, Wimg, b, out);
  } else {
    int total = M * N_DIM;
    naive_kernel<<<(total + 255) / 256, 256, 0, stream>>>(x, W, b, out, total);
  }
}